// Round 2
// baseline (170.418 us; speedup 1.0000x reference)
//
#include <hip/hip_runtime.h>
#include <hip/hip_bf16.h>

namespace {

constexpr int kNXI = 33;                    // x rows tracked: 0..16, 112..127
constexpr int kNY = 16;                     // y modes 0..15
constexpr int kNMODE = kNY * kNXI;          // 528 slots (497 active)

// ws float offsets
constexpr int WS_Q = 0;                     // q[64]
constexpr int WS_ALPHA = 64;
constexpr int WS_GAMMA = 65;
constexpr int WS_S = 68;                    // s[528] complex
constexpr int WS_ZHAT = WS_S + kNMODE * 2;          // Zhat[16][528] complex
constexpr int WS_ZY = WS_ZHAT + 16 * kNMODE * 2;    // Zy[16][128][16] complex
constexpr int WS_T = WS_ZY;                          // alias: T reuses Zy (dead after fwd2)

constexpr float kTheta = 0.04908738521234052f;       // 2*pi/128

// ---------------- prep: q = p2*p1, alpha = q.lw, gamma <- r ----------------
__global__ void fnde_prep(const float* __restrict__ lw,
                          const float* __restrict__ p1w, const float* __restrict__ p1b,
                          const float* __restrict__ p2w, const float* __restrict__ p2b,
                          float* __restrict__ ws) {
  __shared__ float red[64];
  int t = threadIdx.x;
  float qc = 0.f;
  for (int p = 0; p < 64; ++p) qc += p2w[p] * p1w[p * 64 + t];
  ws[WS_Q + t] = qc;
  red[t] = qc * lw[t];
  __syncthreads();
  if (t == 0) {
    float a = 0.f;
    for (int c = 0; c < 64; ++c) a += red[c];
    ws[WS_ALPHA] = a;
    float r = p2b[0];
    for (int p = 0; p < 64; ++p) r += p2w[p] * p1b[p];
    ws[WS_GAMMA] = r;  // mode-00 block adds q.e_final
  }
}

// ---------------- per-mode RK4 evolution of chain vectors ----------------
__global__ __launch_bounds__(256) void fnde_modes(
    const float* __restrict__ w1, const float* __restrict__ w2,
    const float* __restrict__ flb, const float* __restrict__ lw,
    const float* __restrict__ lb, const float* __restrict__ ts,
    float* __restrict__ ws) {
  const int m = blockIdx.x;
  const int y = m / kNXI, xi = m % kNXI;
  const int t = threadIdx.x;

  const bool inactive = (y == 0) ? (xi > 16) : (xi == 16);
  if (inactive) {
    if (t == 0) { ws[WS_S + 2 * m] = 0.f; ws[WS_S + 2 * m + 1] = 0.f; }
    return;
  }

  __shared__ float Wre[4096], Wim[4096];   // layout [i][o]
  __shared__ float zre[2][64], zim[2][64];
  __shared__ float kre[64], kim[64], ure[64], uim[64], accre[64], accim[64];
  __shared__ float red[64];
  __shared__ float tsv[5];

  const bool is00 = (y == 0 && xi == 0);
  const int nch = is00 ? 2 : 1;

  if (t < 64) { zre[0][t] = lw[t]; zim[0][t] = 0.f; }
  if (is00 && t < 64) { zre[1][t] = lb[t]; zim[1][t] = 0.f; }
  if (t < 5) tsv[t] = ts[t];

  const int o = t >> 2, p = t & 3;

  auto matvec = [&](const float* inr, const float* ini, const float* bias) {
    float sre = 0.f, sim = 0.f;
#pragma unroll
    for (int ii = 0; ii < 16; ++ii) {
      int i = (p << 4) + ii;
      float wr = Wre[(i << 6) + o], wi = Wim[(i << 6) + o];
      float xr = inr[i], xii = ini[i];
      sre += wr * xr - wi * xii;
      sim += wr * xii + wi * xr;
    }
    sre += __shfl_xor(sre, 1); sim += __shfl_xor(sim, 1);
    sre += __shfl_xor(sre, 2); sim += __shfl_xor(sim, 2);
    if (p == 0) {
      kre[o] = sre + (bias ? bias[o] : 0.f);
      kim[o] = sim;
    }
    __syncthreads();
  };

  for (int l = 0; l < 3; ++l) {
    // load effective C x C matrix for this (mode, layer) into LDS as W[i][o]
    for (int idx = t; idx < 4096; idx += 256) {
      int i = idx >> 6, oo = idx & 63;
      int off = ((l * 64 + i) * 64 + oo) * 512;  // *M*M*2
      float re, im;
      if (y >= 1) {
        const float* src = (xi <= 15) ? (w1 + off + (xi * 16 + y) * 2)
                                      : (w2 + off + ((xi - 17) * 16 + y) * 2);
        re = src[0]; im = src[1];
      } else {
        float ar = 0.f, ai = 0.f;
        if (xi <= 15) { const float* pa = w1 + off + (xi * 16) * 2; ar = pa[0]; ai = pa[1]; }
        const float* pb = (xi >= 1) ? (w2 + off + ((16 - xi) * 16) * 2) : (w1 + off);
        float br = pb[0], bi = pb[1];
        re = 0.5f * (ar + br);
        im = 0.5f * (ai - bi);   // + conj of partner
      }
      Wre[(i << 6) + oo] = re; Wim[(i << 6) + oo] = im;
    }
    __syncthreads();

    for (int ch = 0; ch < nch; ++ch) {
      float* zr = zre[ch]; float* zi = zim[ch];
      const float* bias = (ch == 1) ? (flb + l * 64) : nullptr;
      for (int st = 0; st < 4; ++st) {
        float h = tsv[st + 1] - tsv[st];
        matvec(zr, zi, bias);                        // k1
        if (t < 64) {
          accre[t] = kre[t]; accim[t] = kim[t];
          ure[t] = zr[t] + 0.5f * h * kre[t]; uim[t] = zi[t] + 0.5f * h * kim[t];
        }
        __syncthreads();
        matvec(ure, uim, bias);                      // k2
        if (t < 64) {
          accre[t] += 2.f * kre[t]; accim[t] += 2.f * kim[t];
          ure[t] = zr[t] + 0.5f * h * kre[t]; uim[t] = zi[t] + 0.5f * h * kim[t];
        }
        __syncthreads();
        matvec(ure, uim, bias);                      // k3
        if (t < 64) {
          accre[t] += 2.f * kre[t]; accim[t] += 2.f * kim[t];
          ure[t] = zr[t] + h * kre[t]; uim[t] = zi[t] + h * kim[t];
        }
        __syncthreads();
        matvec(ure, uim, bias);                      // k4
        if (t < 64) {
          accre[t] += kre[t]; accim[t] += kim[t];
          zr[t] += (h / 6.f) * accre[t]; zi[t] += (h / 6.f) * accim[t];
        }
        __syncthreads();
      }
    }
  }

  // s[m] = q . (a_final - lw)   (complex)
  if (t < 64) red[t] = ws[WS_Q + t] * (zre[0][t] - lw[t]);
  __syncthreads();
  if (t == 0) {
    float s = 0.f;
    for (int c = 0; c < 64; ++c) s += red[c];
    ws[WS_S + 2 * m] = s;
  }
  __syncthreads();
  if (t < 64) red[t] = ws[WS_Q + t] * zim[0][t];
  __syncthreads();
  if (t == 0) {
    float s = 0.f;
    for (int c = 0; c < 64; ++c) s += red[c];
    ws[WS_S + 2 * m + 1] = s;
  }
  if (is00) {
    __syncthreads();
    if (t < 64) red[t] = ws[WS_Q + t] * zre[1][t];
    __syncthreads();
    if (t == 0) {
      float g = ws[WS_GAMMA];
      for (int c = 0; c < 64; ++c) g += red[c];
      ws[WS_GAMMA] = g;
    }
  }
}

// ---------------- forward DFT stage 1: over ys ----------------
__global__ void fnde_fwd1(const float* __restrict__ z, float* __restrict__ ws) {
  const int bid = blockIdx.x;             // b*128 + xs
  const int b = bid >> 7, xs = bid & 127;
  const int t = threadIdx.x;              // 128
  __shared__ float zrow[128], tc[128], tsn[128], rre[128], rim[128];
  sincosf((float)t * kTheta, &tsn[t], &tc[t]);
  zrow[t] = z[b * 16384 + xs * 128 + t];
  __syncthreads();
  int y = t & 15, part = t >> 4;          // 8 partial groups
  float sre = 0.f, sim = 0.f;
  for (int j = 0; j < 16; ++j) {
    int ys = (part << 4) + j;
    int k = (y * ys) & 127;
    float zv = zrow[ys];
    sre += zv * tc[k];
    sim -= zv * tsn[k];
  }
  rre[t] = sre; rim[t] = sim;
  __syncthreads();
  if (t < 16) {
    float ar = 0.f, ai = 0.f;
    for (int pp = 0; pp < 8; ++pp) { ar += rre[(pp << 4) + t]; ai += rim[(pp << 4) + t]; }
    int idx = ((b * 128 + xs) * 16 + t) * 2;
    ws[WS_ZY + idx] = ar; ws[WS_ZY + idx + 1] = ai;
  }
}

// ---------------- forward DFT stage 2: over xs, at tracked x rows ----------------
__global__ void fnde_fwd2(float* __restrict__ ws) {
  const int b = blockIdx.x >> 4, y = blockIdx.x & 15;
  const int t = threadIdx.x;              // 128
  __shared__ float cr[128], ci[128], tc[128], tsn[128];
  sincosf((float)t * kTheta, &tsn[t], &tc[t]);
  int idx = ((b * 128 + t) * 16 + y) * 2;
  cr[t] = ws[WS_ZY + idx]; ci[t] = ws[WS_ZY + idx + 1];
  __syncthreads();
  if (t < kNXI) {
    int x = (t <= 16) ? t : t + 95;
    float ar = 0.f, ai = 0.f;
    for (int xs = 0; xs < 128; ++xs) {
      int k = (x * xs) & 127;
      float c = tc[k], s = tsn[k];
      ar += cr[xs] * c + ci[xs] * s;
      ai += ci[xs] * c - cr[xs] * s;
    }
    int mm = y * kNXI + t;
    ws[WS_ZHAT + (b * kNMODE + mm) * 2] = ar;
    ws[WS_ZHAT + (b * kNMODE + mm) * 2 + 1] = ai;
  }
}

// ---------------- inverse stage 1: over x rows ----------------
__global__ void fnde_inv1(float* __restrict__ ws) {
  const int b = blockIdx.x >> 4, y = blockIdx.x & 15;
  const int t = threadIdx.x;              // 128 (xs)
  __shared__ float Sre[kNXI], Sim[kNXI], tc[128], tsn[128];
  sincosf((float)t * kTheta, &tsn[t], &tc[t]);
  if (t < kNXI) {
    int mm = y * kNXI + t;
    float sr = ws[WS_S + 2 * mm], si = ws[WS_S + 2 * mm + 1];
    float zr = ws[WS_ZHAT + (b * kNMODE + mm) * 2];
    float zi = ws[WS_ZHAT + (b * kNMODE + mm) * 2 + 1];
    Sre[t] = sr * zr - si * zi;
    Sim[t] = sr * zi + si * zr;
  }
  __syncthreads();
  const int xs = t;
  float ar, ai;
  if (y > 0) {
    ar = 0.f; ai = 0.f;
    for (int xi = 0; xi < kNXI; ++xi) {
      int x = (xi <= 16) ? xi : xi + 95;
      int k = (x * xs) & 127;
      float c = tc[k], s = tsn[k];
      ar += Sre[xi] * c - Sim[xi] * s;   // e^{+i}
      ai += Sre[xi] * s + Sim[xi] * c;
    }
  } else {
    ar = Sre[0]; ai = 0.f;               // x-column 0: Hermitian pairs -> real
    for (int xi = 1; xi <= 16; ++xi) {
      int k = (xi * xs) & 127;
      ar += 2.f * (Sre[xi] * tc[k] - Sim[xi] * tsn[k]);
    }
  }
  int idx = ((b * 128 + xs) * 16 + y) * 2;
  ws[WS_T + idx] = ar; ws[WS_T + idx + 1] = ai;
}

// ---------------- inverse stage 2 + epilogue ----------------
__global__ void fnde_final(const float* __restrict__ z, const float* __restrict__ ws,
                           float* __restrict__ out) {
  const int bid = blockIdx.x;             // b*128 + xs
  const int b = bid >> 7, xs = bid & 127;
  const int t = threadIdx.x;              // 128 (ys)
  __shared__ float Tre[16], Tim[16], tc[128], tsn[128];
  sincosf((float)t * kTheta, &tsn[t], &tc[t]);
  if (t < 16) {
    int idx = ((b * 128 + xs) * 16 + t) * 2;
    Tre[t] = ws[WS_T + idx]; Tim[t] = ws[WS_T + idx + 1];
  }
  __syncthreads();
  float acc = Tre[0];
  for (int y = 1; y < 16; ++y) {
    int k = (y * t) & 127;
    acc += 2.f * (Tre[y] * tc[k] - Tim[y] * tsn[k]);   // 2*Re(T * e^{+i})
  }
  float val = ws[WS_ALPHA] * z[b * 16384 + xs * 128 + t] + ws[WS_GAMMA]
            + acc * (1.f / 16384.f);
  out[b * 16384 + xs * 128 + t] = val;
}

}  // namespace

extern "C" void kernel_launch(void* const* d_in, const int* in_sizes, int n_in,
                              void* d_out, int out_size, void* d_ws, size_t ws_size,
                              hipStream_t stream) {
  (void)in_sizes; (void)n_in; (void)out_size; (void)ws_size;
  const float* z   = (const float*)d_in[0];
  const float* lw  = (const float*)d_in[1];
  const float* lb  = (const float*)d_in[2];
  const float* w1  = (const float*)d_in[3];
  const float* w2  = (const float*)d_in[4];
  const float* flb = (const float*)d_in[5];
  const float* p1w = (const float*)d_in[6];
  const float* p1b = (const float*)d_in[7];
  const float* p2w = (const float*)d_in[8];
  const float* p2b = (const float*)d_in[9];
  const float* ts  = (const float*)d_in[10];
  float* ws = (float*)d_ws;
  float* out = (float*)d_out;

  fnde_prep<<<dim3(1), dim3(64), 0, stream>>>(lw, p1w, p1b, p2w, p2b, ws);
  fnde_modes<<<dim3(kNMODE), dim3(256), 0, stream>>>(w1, w2, flb, lw, lb, ts, ws);
  fnde_fwd1<<<dim3(2048), dim3(128), 0, stream>>>(z, ws);
  fnde_fwd2<<<dim3(256), dim3(128), 0, stream>>>(ws);
  fnde_inv1<<<dim3(256), dim3(128), 0, stream>>>(ws);
  fnde_final<<<dim3(2048), dim3(128), 0, stream>>>(z, ws, out);
}

// Round 3
// 145.709 us; speedup vs baseline: 1.1696x; 1.1696x over previous
//
#include <hip/hip_runtime.h>

namespace {

constexpr int kNXI = 33;                    // x rows tracked: 0..16, 112..127
constexpr int kNY = 16;                     // y modes 0..15
constexpr int kNMODE = kNY * kNXI;          // 528 slots (497 active)

// ws float offsets
constexpr int WS_ALPHA = 0;
constexpr int WS_GAMMA = 1;
constexpr int WS_S = 4;                                 // s[528] complex
constexpr int WS_ZY = WS_S + kNMODE * 2;                // Zy[16][128][16] complex
constexpr int WS_T = WS_ZY;                             // T aliases Zy (in-place per (b,y))

constexpr float kTheta = 0.04908738521234052f;          // 2*pi/128

// ---------------- per-mode RK4 evolution of chain vectors ----------------
// Block remap: the 16 y-modes of one xi-column land on ONE XCD (wgid%8 const)
// so the weight cache lines they share (my is innermost in w1/w2) are fetched
// once per XCD L2 instead of ~6x.
__global__ __launch_bounds__(256, 4) void fnde_modes(
    const float* __restrict__ w1, const float* __restrict__ w2,
    const float* __restrict__ flb, const float* __restrict__ lw,
    const float* __restrict__ lb, const float* __restrict__ ts,
    const float* __restrict__ p1w, const float* __restrict__ p1b,
    const float* __restrict__ p2w, const float* __restrict__ p2b,
    float* __restrict__ ws) {
  const int wgd = blockIdx.x;
  const int xcd = wgd & 7, kk0 = wgd >> 3;
  int xi, y;
  if (kk0 < 64) { xi = xcd * 4 + (kk0 >> 4); y = kk0 & 15; }
  else          { xi = 32;                   y = xcd * 2 + (kk0 - 64); }
  const int m = y * kNXI + xi;               // slot in S (consumed by fnde_mid)
  const int t = threadIdx.x;

  const bool inactive = (y == 0) ? (xi > 16) : (xi == 16);
  if (inactive) {
    if (t == 0) { ws[WS_S + 2 * m] = 0.f; ws[WS_S + 2 * m + 1] = 0.f; }
    return;
  }

  __shared__ float Wre[64 * 65], Wim[64 * 65];   // padded: bank = (i+o)%32
  __shared__ float zre[2][64], zim[2][64];
  __shared__ float kre[64], kim[64], ure[64], uim[64], accre[64], accim[64];
  __shared__ float qv[64], red[64];
  __shared__ float tsv[5];

  const bool is00 = (y == 0 && xi == 0);
  const int nch = is00 ? 2 : 1;

  // q = p2*p1 (each block computes its own copy; cheap, removes prep kernel)
  if (t < 64) {
    float qc = 0.f;
    for (int p = 0; p < 64; ++p) qc += p2w[p] * p1w[p * 64 + t];
    qv[t] = qc;
    zre[0][t] = lw[t]; zim[0][t] = 0.f;
  }
  if (is00 && t < 64) { zre[1][t] = lb[t]; zim[1][t] = 0.f; }
  if (t < 5) tsv[t] = ts[t];

  float gbase = 0.f;
  if (is00 && t == 0) {
    float r = p2b[0];
    for (int p = 0; p < 64; ++p) r += p2w[p] * p1b[p];
    gbase = r;
  }

  // ---- staging: register prefetch for y>=1 (single source stream) ----
  const float* srcbase = nullptr;
  int moff = 0;
  if (y >= 1) {
    if (xi <= 15) { srcbase = w1; moff = (xi * 16 + y) * 2; }
    else          { srcbase = w2; moff = ((xi - 17) * 16 + y) * 2; }
  }
  float2 pf[16];

  auto issue = [&](int l) {
#pragma unroll
    for (int kk = 0; kk < 16; ++kk) {
      int idx = t + kk * 256;
      pf[kk] = *reinterpret_cast<const float2*>(
          srcbase + (size_t)(l * 4096 + idx) * 512 + moff);
    }
  };
  auto commit = [&]() {
#pragma unroll
    for (int kk = 0; kk < 16; ++kk) {
      int idx = t + kk * 256;
      int i = idx >> 6, oo = idx & 63;
      Wre[i * 65 + oo] = pf[kk].x;
      Wim[i * 65 + oo] = pf[kk].y;
    }
  };
  auto stage0 = [&](int l) {   // y==0: Hermitian combine of w1 and conj(w2 partner)
    for (int idx = t; idx < 4096; idx += 256) {
      int i = idx >> 6, oo = idx & 63;
      size_t off = (size_t)((l * 64 + i) * 64 + oo) * 512;
      float ar = 0.f, ai = 0.f;
      if (xi <= 15) { const float* pa = w1 + off + (xi * 16) * 2; ar = pa[0]; ai = pa[1]; }
      const float* pb = (xi >= 1) ? (w2 + off + ((16 - xi) * 16) * 2) : (w1 + off);
      Wre[i * 65 + oo] = 0.5f * (ar + pb[0]);
      Wim[i * 65 + oo] = 0.5f * (ai - pb[1]);
    }
  };

  const int o = t >> 2, p = t & 3;

  auto matvec = [&](const float* inr, const float* ini, const float* bias) {
    float sre = 0.f, sim = 0.f;
#pragma unroll
    for (int ii = 0; ii < 16; ++ii) {
      int i = (p << 4) + ii;
      float wr = Wre[i * 65 + o], wi = Wim[i * 65 + o];
      float xr = inr[i], xii = ini[i];
      sre += wr * xr - wi * xii;
      sim += wr * xii + wi * xr;
    }
    sre += __shfl_xor(sre, 1); sim += __shfl_xor(sim, 1);
    sre += __shfl_xor(sre, 2); sim += __shfl_xor(sim, 2);
    if (p == 0) {
      kre[o] = sre + (bias ? bias[o] : 0.f);
      kim[o] = sim;
    }
    __syncthreads();
  };

  if (y >= 1) issue(0);

  for (int l = 0; l < 3; ++l) {
    __syncthreads();                       // prev layer's LDS readers done + init visible
    if (y >= 1) { commit(); if (l < 2) issue(l + 1); }
    else        { stage0(l); }
    __syncthreads();

    // alpha once, after qv/z visible (overlaps with nothing critical)
    if (l == 0 && is00 && t == 0) {
      float a = 0.f;
      for (int c = 0; c < 64; ++c) a += qv[c] * zre[0][c];
      ws[WS_ALPHA] = a;
    }

    for (int ch = 0; ch < nch; ++ch) {
      float* zr = zre[ch]; float* zi = zim[ch];
      const float* bias = (ch == 1) ? (flb + l * 64) : nullptr;
      for (int st = 0; st < 4; ++st) {
        float h = tsv[st + 1] - tsv[st];
        matvec(zr, zi, bias);                        // k1
        if (t < 64) {
          accre[t] = kre[t]; accim[t] = kim[t];
          ure[t] = zr[t] + 0.5f * h * kre[t]; uim[t] = zi[t] + 0.5f * h * kim[t];
        }
        __syncthreads();
        matvec(ure, uim, bias);                      // k2
        if (t < 64) {
          accre[t] += 2.f * kre[t]; accim[t] += 2.f * kim[t];
          ure[t] = zr[t] + 0.5f * h * kre[t]; uim[t] = zi[t] + 0.5f * h * kim[t];
        }
        __syncthreads();
        matvec(ure, uim, bias);                      // k3
        if (t < 64) {
          accre[t] += 2.f * kre[t]; accim[t] += 2.f * kim[t];
          ure[t] = zr[t] + h * kre[t]; uim[t] = zi[t] + h * kim[t];
        }
        __syncthreads();
        matvec(ure, uim, bias);                      // k4
        if (t < 64) {
          accre[t] += kre[t]; accim[t] += kim[t];
          zr[t] += (h / 6.f) * accre[t]; zi[t] += (h / 6.f) * accim[t];
        }
        __syncthreads();
      }
    }
  }

  // s[m] = q . (a_final - lw)   (complex)
  if (t < 64) red[t] = qv[t] * (zre[0][t] - lw[t]);
  __syncthreads();
  if (t == 0) {
    float s = 0.f;
    for (int c = 0; c < 64; ++c) s += red[c];
    ws[WS_S + 2 * m] = s;
  }
  __syncthreads();
  if (t < 64) red[t] = qv[t] * zim[0][t];
  __syncthreads();
  if (t == 0) {
    float s = 0.f;
    for (int c = 0; c < 64; ++c) s += red[c];
    ws[WS_S + 2 * m + 1] = s;
  }
  if (is00) {
    __syncthreads();
    if (t < 64) red[t] = qv[t] * zre[1][t];
    __syncthreads();
    if (t == 0) {
      float g = gbase;
      for (int c = 0; c < 64; ++c) g += red[c];
      ws[WS_GAMMA] = g;
    }
  }
}

// ---------------- forward DFT stage 1: over ys ----------------
__global__ void fnde_fwd1(const float* __restrict__ z, float* __restrict__ ws) {
  const int bid = blockIdx.x;             // b*128 + xs
  const int b = bid >> 7, xs = bid & 127;
  const int t = threadIdx.x;              // 128
  __shared__ float zrow[128], tc[128], tsn[128], rre[128], rim[128];
  sincosf((float)t * kTheta, &tsn[t], &tc[t]);
  zrow[t] = z[b * 16384 + xs * 128 + t];
  __syncthreads();
  int y = t & 15, part = t >> 4;          // 8 partial groups
  float sre = 0.f, sim = 0.f;
  for (int j = 0; j < 16; ++j) {
    int ys = (part << 4) + j;
    int k = (y * ys) & 127;
    float zv = zrow[ys];
    sre += zv * tc[k];
    sim -= zv * tsn[k];
  }
  rre[t] = sre; rim[t] = sim;
  __syncthreads();
  if (t < 16) {
    float ar = 0.f, ai = 0.f;
    for (int pp = 0; pp < 8; ++pp) { ar += rre[(pp << 4) + t]; ai += rim[(pp << 4) + t]; }
    int idx = ((b * 128 + xs) * 16 + t) * 2;
    ws[WS_ZY + idx] = ar; ws[WS_ZY + idx + 1] = ai;
  }
}

// ---------------- fused: x-DFT at tracked rows, *S, inverse over xs ----------------
__global__ void fnde_mid(float* __restrict__ ws) {
  const int b = blockIdx.x >> 4, y = blockIdx.x & 15;
  const int t = threadIdx.x;              // 128
  __shared__ float cr[128], ci[128], tc[128], tsn[128], Sre[kNXI], Sim[kNXI];
  sincosf((float)t * kTheta, &tsn[t], &tc[t]);
  int idx = ((b * 128 + t) * 16 + y) * 2;
  cr[t] = ws[WS_ZY + idx]; ci[t] = ws[WS_ZY + idx + 1];
  __syncthreads();
  if (t < kNXI) {
    int x = (t <= 16) ? t : t + 95;
    float ar = 0.f, ai = 0.f;
    for (int xs = 0; xs < 128; ++xs) {
      int k = (x * xs) & 127;
      float c = tc[k], s = tsn[k];
      ar += cr[xs] * c + ci[xs] * s;
      ai += ci[xs] * c - cr[xs] * s;
    }
    int mm = y * kNXI + t;
    float sr = ws[WS_S + 2 * mm], si = ws[WS_S + 2 * mm + 1];
    Sre[t] = sr * ar - si * ai;
    Sim[t] = sr * ai + si * ar;
  }
  __syncthreads();
  const int xs = t;
  float ar, ai;
  if (y > 0) {
    ar = 0.f; ai = 0.f;
    for (int xi = 0; xi < kNXI; ++xi) {
      int x = (xi <= 16) ? xi : xi + 95;
      int k = (x * xs) & 127;
      float c = tc[k], s = tsn[k];
      ar += Sre[xi] * c - Sim[xi] * s;   // e^{+i}
      ai += Sre[xi] * s + Sim[xi] * c;
    }
  } else {
    ar = Sre[0]; ai = 0.f;               // x-col 0: Hermitian pairs -> real
    for (int xi = 1; xi <= 16; ++xi) {
      int k = (xi * xs) & 127;
      ar += 2.f * (Sre[xi] * tc[k] - Sim[xi] * tsn[k]);
    }
  }
  ws[WS_T + idx] = ar; ws[WS_T + idx + 1] = ai;   // in-place per (b,y) slice
}

// ---------------- inverse stage 2 + epilogue ----------------
__global__ void fnde_final(const float* __restrict__ z, const float* __restrict__ ws,
                           float* __restrict__ out) {
  const int bid = blockIdx.x;             // b*128 + xs
  const int b = bid >> 7, xs = bid & 127;
  const int t = threadIdx.x;              // 128 (ys)
  __shared__ float Tre[16], Tim[16], tc[128], tsn[128];
  sincosf((float)t * kTheta, &tsn[t], &tc[t]);
  if (t < 16) {
    int idx = ((b * 128 + xs) * 16 + t) * 2;
    Tre[t] = ws[WS_T + idx]; Tim[t] = ws[WS_T + idx + 1];
  }
  __syncthreads();
  float acc = Tre[0];
  for (int y = 1; y < 16; ++y) {
    int k = (y * t) & 127;
    acc += 2.f * (Tre[y] * tc[k] - Tim[y] * tsn[k]);   // 2*Re(T * e^{+i})
  }
  float val = ws[WS_ALPHA] * z[b * 16384 + xs * 128 + t] + ws[WS_GAMMA]
            + acc * (1.f / 16384.f);
  out[b * 16384 + xs * 128 + t] = val;
}

}  // namespace

extern "C" void kernel_launch(void* const* d_in, const int* in_sizes, int n_in,
                              void* d_out, int out_size, void* d_ws, size_t ws_size,
                              hipStream_t stream) {
  (void)in_sizes; (void)n_in; (void)out_size; (void)ws_size;
  const float* z   = (const float*)d_in[0];
  const float* lw  = (const float*)d_in[1];
  const float* lb  = (const float*)d_in[2];
  const float* w1  = (const float*)d_in[3];
  const float* w2  = (const float*)d_in[4];
  const float* flb = (const float*)d_in[5];
  const float* p1w = (const float*)d_in[6];
  const float* p1b = (const float*)d_in[7];
  const float* p2w = (const float*)d_in[8];
  const float* p2b = (const float*)d_in[9];
  const float* ts  = (const float*)d_in[10];
  float* ws = (float*)d_ws;
  float* out = (float*)d_out;

  fnde_modes<<<dim3(kNMODE), dim3(256), 0, stream>>>(w1, w2, flb, lw, lb, ts,
                                                     p1w, p1b, p2w, p2b, ws);
  fnde_fwd1<<<dim3(2048), dim3(128), 0, stream>>>(z, ws);
  fnde_mid<<<dim3(256), dim3(128), 0, stream>>>(ws);
  fnde_final<<<dim3(2048), dim3(128), 0, stream>>>(z, ws, out);
}